// Round 1
// baseline (239.904 us; speedup 1.0000x reference)
//
#include <hip/hip_runtime.h>

// MomentumLIF: x[N,T,D] f32 -> spikes[N,T,D] f32 (0/1)
//   v_t = mom*v + x_t - lamb*u ; u_t = 0.5*u + v_t ; s = (u>=1); u *= (1-s)
// Parallel over N*D chains, sequential over T. Memory-bound: 256 MiB traffic.

#define N_ 64
#define T_ 64
#define D_ 8192

__global__ __launch_bounds__(256) void MomentumLIF_kernel(
    const float* __restrict__ x,
    const float* __restrict__ momp,
    const float* __restrict__ lambp,
    float* __restrict__ out)
{
    // Match numpy f32 semantics exactly: no FMA contraction anywhere in here.
#pragma clang fp contract(off)
    const float mom  = momp[0];
    const float lamb = lambp[0];
    const float decay = 0.5f;   // 1 - 1/TAU, exact

    const int tid = blockIdx.x * blockDim.x + threadIdx.x;  // [0, N*D/4)
    const int n  = tid >> 11;        // D_/4 = 2048 float4 per row
    const int d4 = tid & 2047;

    const float4* __restrict__ xv =
        reinterpret_cast<const float4*>(x + (size_t)n * T_ * D_) + d4;
    float4* __restrict__ ov =
        reinterpret_cast<float4*>(out + (size_t)n * T_ * D_) + d4;

    constexpr int S = D_ / 4;        // float4 stride between timesteps

    float u0 = 0.f, u1 = 0.f, u2 = 0.f, u3 = 0.f;
    float v0 = 0.f, v1 = 0.f, v2 = 0.f, v3 = 0.f;

#pragma unroll 4
    for (int t = 0; t < T_; ++t) {
        const float4 xt = xv[(size_t)t * S];
        float4 s;

        // component 0
        {
            float t1 = mom * v0;           // separately rounded, matches numpy
            float t2 = lamb * u0;
            v0 = (t1 + xt.x) - t2;
            u0 = decay * u0 + v0;
            const bool sp = (u0 >= 1.0f);
            s.x = sp ? 1.0f : 0.0f;
            u0  = sp ? 0.0f : u0;          // u*(1-s) is exactly this select
        }
        // component 1
        {
            float t1 = mom * v1;
            float t2 = lamb * u1;
            v1 = (t1 + xt.y) - t2;
            u1 = decay * u1 + v1;
            const bool sp = (u1 >= 1.0f);
            s.y = sp ? 1.0f : 0.0f;
            u1  = sp ? 0.0f : u1;
        }
        // component 2
        {
            float t1 = mom * v2;
            float t2 = lamb * u2;
            v2 = (t1 + xt.z) - t2;
            u2 = decay * u2 + v2;
            const bool sp = (u2 >= 1.0f);
            s.z = sp ? 1.0f : 0.0f;
            u2  = sp ? 0.0f : u2;
        }
        // component 3
        {
            float t1 = mom * v3;
            float t2 = lamb * u3;
            v3 = (t1 + xt.w) - t2;
            u3 = decay * u3 + v3;
            const bool sp = (u3 >= 1.0f);
            s.w = sp ? 1.0f : 0.0f;
            u3  = sp ? 0.0f : u3;
        }

        ov[(size_t)t * S] = s;
    }
}

extern "C" void kernel_launch(void* const* d_in, const int* in_sizes, int n_in,
                              void* d_out, int out_size, void* d_ws, size_t ws_size,
                              hipStream_t stream) {
    const float* x    = (const float*)d_in[0];
    const float* momp = (const float*)d_in[1];
    const float* lamb = (const float*)d_in[2];
    float* out = (float*)d_out;

    const int threads = (N_ * D_) / 4;   // 131072 lanes, float4 each
    dim3 block(256);
    dim3 grid(threads / 256);            // 512 blocks
    hipLaunchKernelGGL(MomentumLIF_kernel, grid, block, 0, stream,
                       x, momp, lamb, out);
}